// Round 12
// baseline (275.107 us; speedup 1.0000x reference)
//
#include <hip/hip_runtime.h>
#include <math.h>

#define HID 256
#define EPS_REG 1e-6

typedef __attribute__((ext_vector_type(8))) short short8;
typedef __attribute__((ext_vector_type(4))) short short4v;
typedef __attribute__((ext_vector_type(4))) float v4f;

#define MFMA_BF16(a, b, c) __builtin_amdgcn_mfma_f32_16x16x32_bf16((a), (b), (c), 0, 0, 0)

// ---------------------------------------------------------------------------
// Fast tanh: tanh(z) = 1 - 2/(exp(2z)+1). ~6 instr, <=2 ulp.
// ---------------------------------------------------------------------------
__device__ __forceinline__ float fast_tanh(float z) {
    const float e = __expf(2.0f * z);
    const float d = e + 1.0f;
    float r = __builtin_amdgcn_rcpf(d);
    r = r * (2.0f - d * r);              // Newton refine to full fp32
    return fmaf(-2.0f, r, 1.0f);
}

// ---------------------------------------------------------------------------
// Cheap RTN bf16 3-way split: v ~= hi + mid + lo (round-half-up, 2 ops/stage).
// ---------------------------------------------------------------------------
__device__ __forceinline__ float rtn_bf16(float v, short* s) {
    unsigned r = (__float_as_uint(v) + 0x8000u) & 0xFFFF0000u;
    *s = (short)(r >> 16);
    return __uint_as_float(r);
}
__device__ __forceinline__ void split3(float v, short* a, short* b, short* c) {
    float f0 = rtn_bf16(v, a);
    float r1 = v - f0;
    float f1 = rtn_bf16(r1, b);
    float r2 = r1 - f1;
    (void)rtn_bf16(r2, c);
}

// ---------------------------------------------------------------------------
// Prep: split W1 into bf16 hi/mid/lo laid out as per-lane MFMA A-fragments
// for phase 1 (A = W1 rows) and phase 2 (A = W1 columns). 6 x 128KB = 768KB.
// ---------------------------------------------------------------------------
__global__ void prep_w1_frags(const float* __restrict__ W1, short* __restrict__ ws) {
    const int gid   = blockIdx.x * 128 + threadIdx.x;   // 0..16383
    const int lane  = gid & 63;
    const int ks    = (gid >> 6) & 7;
    const int rt    = (gid >> 9) & 15;
    const int which = gid >> 13;                        // 0: A1, 1: A2
    const int m = lane & 15, q = lane >> 4;

    float v[8];
    if (which == 0) {
        const float* p = W1 + (size_t)(rt*16 + m)*HID + ks*32 + q*8;
        const float4 va = *(const float4*)(p);
        const float4 vb = *(const float4*)(p + 4);
        v[0]=va.x; v[1]=va.y; v[2]=va.z; v[3]=va.w;
        v[4]=vb.x; v[5]=vb.y; v[6]=vb.z; v[7]=vb.w;
    } else {
        const float* p = W1 + (size_t)(ks*32 + q*8)*HID + rt*16 + m;
#pragma unroll
        for (int t = 0; t < 8; ++t) v[t] = p[(size_t)t*HID];
    }
    short8 h8, m8, l8;
#pragma unroll
    for (int t = 0; t < 8; ++t) {
        short sh, sm, sl;
        split3(v[t], &sh, &sm, &sl);
        h8[t] = sh; m8[t] = sm; l8[t] = sl;
    }
    const size_t base = (size_t)which*3*65536 + ((size_t)(rt*8 + ks)*64 + lane)*8;
    *(short8*)(ws + base)          = h8;
    *(short8*)(ws + base + 65536)  = m8;
    *(short8*)(ws + base + 131072) = l8;
}

// ---------------------------------------------------------------------------
// MFMA main kernel: 8 samples/block (N=32 = 2 col-tiles), 512 threads = 8
// waves (2 row-tiles/wave), 2 blocks/CU -> 4 waves/SIMD.
// bf16x3 / 6-product fp32 emulation on 16x16x32 MFMA.
// B-frag layout: addr = G*136 + c*8 + (k&7), G = k>>3 (16B pad per group).
// R12: U0 slot XOR-swizzle s' = s ^ ((j>>3)&7): phase-3 float4 reads at
// stride-36 were 8-way bank conflicts (lanes t, t+8 shared banks); the
// swizzle gives the 8 colliding lanes 8 distinct slot offsets -> conflict-
// free. Epi-2 writes stay 2-way. Pure permutation: bit-identical results.
// ---------------------------------------------------------------------------
#define FRAG_NT_STRIDE 13056   // 3 bufs * 32 groups * 136 shorts
#define FRAG_BUF_STRIDE 4352   // 32 groups * 136

__global__ __launch_bounds__(512, 4)
void lnn_mfma(const float* __restrict__ x,
              const float* __restrict__ W0, const float* __restrict__ b0,
              const float* __restrict__ b1, const float* __restrict__ W2,
              const short* __restrict__ ws,
              float* __restrict__ out)
{
    __shared__ __align__(16) short Bfrag[26112];     // 52224 B
    __shared__ float M0h[HID * 9];                   // h0 per (j, s), stride 9

    const int tid   = threadIdx.x;
    const int samp0 = blockIdx.x * 8;
    const int lane  = tid & 63;
    const int w     = tid >> 6;                      // wave 0..7

    // ---- Phase 0: layer-0 forward + tangents --> M0h + B1 frags -----------
    {
        const int j  = tid & 255;
        const int s0 = (tid >> 8) * 4;
        float w0r[7];
#pragma unroll
        for (int d = 0; d < 7; ++d) w0r[d] = W0[j*7 + d];
        const float bj = b0[j];
        const int kbase = (j >> 3)*136 + (j & 7);    // G*136 + t
#pragma unroll
        for (int si = 0; si < 4; ++si) {
            const int s = s0 + si;
            const float* xs = x + (size_t)(samp0 + s)*7;
            float z = bj;
#pragma unroll
            for (int d = 0; d < 7; ++d) z = fmaf(w0r[d], xs[d], z);
            const float h  = fast_tanh(z);
            const float sg = 1.0f - h*h;
            M0h[j*9 + s] = h;
            const int nt = s >> 2;
            const int cb = (s & 3) * 4;              // col base within tile
            float vals[4] = {h, sg*w0r[4], sg*w0r[5], sg*w0r[6]};
#pragma unroll
            for (int comp = 0; comp < 4; ++comp) {
                short sh, sm, sl;
                split3(vals[comp], &sh, &sm, &sl);
                const int a = nt*FRAG_NT_STRIDE + kbase + (cb + comp)*8;
                Bfrag[a]                    = sh;
                Bfrag[a + FRAG_BUF_STRIDE]  = sm;
                Bfrag[a + 2*FRAG_BUF_STRIDE]= sl;
            }
        }
    }
    __syncthreads();

    const short8* A1h = (const short8*)ws;
    const short8* A1m = A1h + 8192;
    const short8* A1l = A1h + 16384;
    const short8* A2h = A1h + 24576;
    const short8* A2m = A1h + 32768;
    const short8* A2l = A1h + 40960;

    const int q = lane >> 4;        // C/D row-quad; also B k-octet
    const int c = lane & 15;        // C/D & B col
    const int boff = q*136 + c*8;   // per-lane B-frag offset within (nt,buf,ks=0)

    // ---- Phase 1: Z = W1 x M  (rows i = (w*2+rtl)*16 + q*4 + reg) ---------
    v4f acc[2][2];
#pragma unroll
    for (int rtl = 0; rtl < 2; ++rtl)
#pragma unroll
        for (int nt = 0; nt < 2; ++nt) acc[rtl][nt] = (v4f){0.f, 0.f, 0.f, 0.f};

    {
        short8 pah[2][2], pam[2][2], pal[2][2];   // [parity][rtl] A prefetch
#pragma unroll
        for (int rtl = 0; rtl < 2; ++rtl) {
            const size_t fi = ((size_t)((w*2 + rtl)*8))*64 + lane;
            pah[0][rtl] = A1h[fi]; pam[0][rtl] = A1m[fi]; pal[0][rtl] = A1l[fi];
        }
#pragma unroll
        for (int ks = 0; ks < 8; ++ks) {
            const int cur = ks & 1, nxt = cur ^ 1;
            if (ks < 7) {
#pragma unroll
                for (int rtl = 0; rtl < 2; ++rtl) {
                    const size_t fi = ((size_t)((w*2 + rtl)*8 + ks + 1))*64 + lane;
                    pah[nxt][rtl] = A1h[fi]; pam[nxt][rtl] = A1m[fi]; pal[nxt][rtl] = A1l[fi];
                }
            }
            short8 bh[2], bm[2], bl[2];
#pragma unroll
            for (int nt = 0; nt < 2; ++nt) {
                const int a = nt*FRAG_NT_STRIDE + ks*544 + boff;
                bh[nt] = *(const short8*)(&Bfrag[a]);
                bm[nt] = *(const short8*)(&Bfrag[a + FRAG_BUF_STRIDE]);
                bl[nt] = *(const short8*)(&Bfrag[a + 2*FRAG_BUF_STRIDE]);
            }
#pragma unroll
            for (int rtl = 0; rtl < 2; ++rtl) {
                const short8 ah = pah[cur][rtl];
                const short8 am = pam[cur][rtl];
                const short8 al = pal[cur][rtl];
#pragma unroll
                for (int nt = 0; nt < 2; ++nt) {
                    acc[rtl][nt] = MFMA_BF16(ah, bl[nt], acc[rtl][nt]);
                    acc[rtl][nt] = MFMA_BF16(al, bh[nt], acc[rtl][nt]);
                    acc[rtl][nt] = MFMA_BF16(am, bm[nt], acc[rtl][nt]);
                    acc[rtl][nt] = MFMA_BF16(am, bh[nt], acc[rtl][nt]);
                    acc[rtl][nt] = MFMA_BF16(ah, bm[nt], acc[rtl][nt]);
                    acc[rtl][nt] = MFMA_BF16(ah, bh[nt], acc[rtl][nt]);
                }
            }
        }
    }
    __syncthreads();   // all waves done reading B1 frags

    // ---- Epilogue 1: layer-2 nonlinearity + reverse seed --> B2 frags -----
    {
        const int myreg = c & 3;
#pragma unroll
        for (int rtl = 0; rtl < 2; ++rtl) {
            const int base = (w*2 + rtl)*16;
            float b1r[4], w2r[4];
#pragma unroll
            for (int r = 0; r < 4; ++r) {
                b1r[r] = b1[base + q*4 + r];
                w2r[r] = W2[base + q*4 + r];
            }
            const int G  = (base >> 3) + (q >> 1);
            const int tq = (q & 1) * 4;
#pragma unroll
            for (int nt = 0; nt < 2; ++nt) {
                short4v ph, pm, pl;
#pragma unroll
                for (int r = 0; r < 4; ++r) {
                    const float z0 = __shfl(acc[rtl][nt][r] + b1r[r], lane & ~3, 64);
                    const float h1 = fast_tanh(z0);
                    const float s1 = 1.0f - h1*h1;
                    const float av = acc[rtl][nt][r];
                    const float u  = (myreg == 0) ? (w2r[r]*s1)
                                                  : (-2.0f*w2r[r]*h1*s1)*av;
                    short sh, sm, sl;
                    split3(u, &sh, &sm, &sl);
                    ph[r] = sh; pm[r] = sm; pl[r] = sl;
                }
                const int a = nt*FRAG_NT_STRIDE + G*136 + c*8 + tq;
                *(short4v*)(&Bfrag[a])                     = ph;
                *(short4v*)(&Bfrag[a + FRAG_BUF_STRIDE])   = pm;
                *(short4v*)(&Bfrag[a + 2*FRAG_BUF_STRIDE]) = pl;
            }
        }
    }
    __syncthreads();

    // ---- Phase 2: P = W1^T x U  (rows j = (w*2+rtl)*16 + q*4 + reg) -------
    v4f acc2[2][2];
#pragma unroll
    for (int rtl = 0; rtl < 2; ++rtl)
#pragma unroll
        for (int nt = 0; nt < 2; ++nt) acc2[rtl][nt] = (v4f){0.f, 0.f, 0.f, 0.f};

    {
        short8 pah[2][2], pam[2][2], pal[2][2];
#pragma unroll
        for (int rtl = 0; rtl < 2; ++rtl) {
            const size_t fi = ((size_t)((w*2 + rtl)*8))*64 + lane;
            pah[0][rtl] = A2h[fi]; pam[0][rtl] = A2m[fi]; pal[0][rtl] = A2l[fi];
        }
#pragma unroll
        for (int ks = 0; ks < 8; ++ks) {
            const int cur = ks & 1, nxt = cur ^ 1;
            if (ks < 7) {
#pragma unroll
                for (int rtl = 0; rtl < 2; ++rtl) {
                    const size_t fi = ((size_t)((w*2 + rtl)*8 + ks + 1))*64 + lane;
                    pah[nxt][rtl] = A2h[fi]; pam[nxt][rtl] = A2m[fi]; pal[nxt][rtl] = A2l[fi];
                }
            }
            short8 bh[2], bm[2], bl[2];
#pragma unroll
            for (int nt = 0; nt < 2; ++nt) {
                const int a = nt*FRAG_NT_STRIDE + ks*544 + boff;
                bh[nt] = *(const short8*)(&Bfrag[a]);
                bm[nt] = *(const short8*)(&Bfrag[a + FRAG_BUF_STRIDE]);
                bl[nt] = *(const short8*)(&Bfrag[a + 2*FRAG_BUF_STRIDE]);
            }
#pragma unroll
            for (int rtl = 0; rtl < 2; ++rtl) {
                const short8 ah = pah[cur][rtl];
                const short8 am = pam[cur][rtl];
                const short8 al = pal[cur][rtl];
#pragma unroll
                for (int nt = 0; nt < 2; ++nt) {
                    acc2[rtl][nt] = MFMA_BF16(ah, bl[nt], acc2[rtl][nt]);
                    acc2[rtl][nt] = MFMA_BF16(al, bh[nt], acc2[rtl][nt]);
                    acc2[rtl][nt] = MFMA_BF16(am, bm[nt], acc2[rtl][nt]);
                    acc2[rtl][nt] = MFMA_BF16(am, bh[nt], acc2[rtl][nt]);
                    acc2[rtl][nt] = MFMA_BF16(ah, bm[nt], acc2[rtl][nt]);
                    acc2[rtl][nt] = MFMA_BF16(ah, bh[nt], acc2[rtl][nt]);
                }
            }
        }
    }
    __syncthreads();   // all waves done reading B2 frags

    // ---- Epilogue 2: back through layer-0 --> U0 plain (overlay Bfrag) ----
    // U0 slot swizzle: slot s' = s ^ ((j>>3)&7); word = j*36 + s'*4 + comp.
    {
        float* U0 = (float*)Bfrag;
#pragma unroll
        for (int rtl = 0; rtl < 2; ++rtl) {
#pragma unroll
            for (int reg = 0; reg < 4; ++reg) {
                const int j = (w*2 + rtl)*16 + q*4 + reg;
                const int gsw = (j >> 3) & 7;
                const float w0sel = W0[j*7 + 3 + (c & 3)];  // dummy read for comp 0
#pragma unroll
                for (int nt = 0; nt < 2; ++nt) {
                    const int s = nt*4 + (c >> 2);
                    const float pv = acc2[rtl][nt][reg];
                    const float p0 = __shfl(pv, lane & ~3, 64);
                    const float h0 = M0h[j*9 + s];
                    const float sg = 1.0f - h0*h0;
                    const float t2 = -2.0f * p0 * h0 * sg;
                    const float res = ((c & 3) == 0) ? (p0*sg)
                                                     : fmaf(pv, sg, t2 * w0sel);
                    U0[j*36 + (s ^ gsw)*4 + (c & 3)] = res;
                }
            }
        }
    }
    __syncthreads();

    // ---- Phase 3: project through W0^T, reduce, assemble, solve -----------
    const float* U0 = (const float*)Bfrag;
    float* scratch = ((float*)Bfrag) + 9216 + w * 425;   // [25][17]
    const int s = w;            // sample (0..7) = wave id
    const int t = tid & 63;
    float part[25];
#pragma unroll
    for (int qq = 0; qq < 25; ++qq) part[qq] = 0.0f;

#pragma unroll
    for (int m = 0; m < 4; ++m) {
        const int j = t + 64*m;
        const int gsw = (j >> 3) & 7;        // == ((t>>3)&7), constant in m
        const float4 uv = *(const float4*)(&U0[j*36 + (s ^ gsw)*4]);
        float w0d[7];
#pragma unroll
        for (int d = 0; d < 7; ++d) w0d[d] = W0[j*7 + d];
#pragma unroll
        for (int d = 0; d < 4; ++d) part[d] = fmaf(uv.x, w0d[d], part[d]);
#pragma unroll
        for (int d = 0; d < 7; ++d) {
            part[4  + d] = fmaf(uv.y, w0d[d], part[4  + d]);
            part[11 + d] = fmaf(uv.z, w0d[d], part[11 + d]);
            part[18 + d] = fmaf(uv.w, w0d[d], part[18 + d]);
        }
    }
    // stages 1-2: quad-local sums
#pragma unroll
    for (int off = 1; off <= 2; off <<= 1)
#pragma unroll
        for (int qq = 0; qq < 25; ++qq)
            part[qq] += __shfl_xor(part[qq], off, 64);
    {
        const int quad = t >> 2;
        if ((t & 3) == 0) {
#pragma unroll
            for (int e = 0; e < 25; ++e)
                scratch[e*17 + quad] = part[e];
        }
    }
    if (t < 25) {
        float tot = 0.0f;
#pragma unroll
        for (int k = 0; k < 16; ++k) tot += scratch[t*17 + k];
        scratch[t*17 + 16] = tot;
    }

    if (t == 0) {
        double g[25];
#pragma unroll
        for (int e = 0; e < 25; ++e) g[e] = (double)scratch[e*17 + 16];

        const float* xs = x + (size_t)(samp0 + s)*7;
        const double x1 = xs[2], x2 = xs[3];
        const double dq0 = xs[4], dq1 = xs[5], dth = xs[6];

        double M[3][3], rhs[3];
#pragma unroll
        for (int i = 0; i < 3; ++i) {
            const double J0 = g[4 + i*7 + 0];
            const double J1 = g[4 + i*7 + 1];
            const double J2 = -x2*g[4 + i*7 + 2] + x1*g[4 + i*7 + 3];
            const double dL = (i == 0) ? g[0]
                            : (i == 1) ? g[1]
                            : (-x2*g[2] + x1*g[3]);
            M[i][0] = g[4 + i*7 + 4] + (i == 0 ? EPS_REG : 0.0);
            M[i][1] = g[4 + i*7 + 5] + (i == 1 ? EPS_REG : 0.0);
            M[i][2] = g[4 + i*7 + 6] + (i == 2 ? EPS_REG : 0.0);
            rhs[i]  = dL - (J0*dq0 + J1*dq1 + J2*dth);
        }
        // branch-free fp64 Cramer / adjugate solve
        const double c00 = M[1][1]*M[2][2] - M[1][2]*M[2][1];
        const double c01 = M[1][2]*M[2][0] - M[1][0]*M[2][2];
        const double c02 = M[1][0]*M[2][1] - M[1][1]*M[2][0];
        const double det = M[0][0]*c00 + M[0][1]*c01 + M[0][2]*c02;
        const double inv = 1.0 / det;
        const double c10 = M[0][2]*M[2][1] - M[0][1]*M[2][2];
        const double c11 = M[0][0]*M[2][2] - M[0][2]*M[2][0];
        const double c12 = M[0][1]*M[2][0] - M[0][0]*M[2][1];
        const double c20 = M[0][1]*M[1][2] - M[0][2]*M[1][1];
        const double c21 = M[0][2]*M[1][0] - M[0][0]*M[1][2];
        const double c22 = M[0][0]*M[1][1] - M[0][1]*M[1][0];
        const double sol0 = (c00*rhs[0] + c10*rhs[1] + c20*rhs[2]) * inv;
        const double sol1 = (c01*rhs[0] + c11*rhs[1] + c21*rhs[2]) * inv;
        const double sol2 = (c02*rhs[0] + c12*rhs[1] + c22*rhs[2]) * inv;

        float* o = out + (size_t)(samp0 + s)*7;
        o[0] = (float)dq0;
        o[1] = (float)dq1;
        o[2] = (float)(-x2*dth);
        o[3] = (float)( x1*dth);
        o[4] = (float)sol0;
        o[5] = (float)sol1;
        o[6] = (float)sol2;
    }
}

// ===========================================================================
// Fallback path (proven round-3 kernel, fp32 VALU): used if ws_size < 768KB.
// ===========================================================================
#define TS8 8
#define SCP 36

__global__ void transpose_w1(const float* __restrict__ W1, float* __restrict__ W1T) {
    __shared__ float tile[32][33];
    const int bx = blockIdx.x & 7;
    const int by = blockIdx.x >> 3;
    const int tx = threadIdx.x & 31;
    const int ty = threadIdx.x >> 5;
#pragma unroll
    for (int q = 0; q < 4; ++q)
        tile[ty + q*8][tx] = W1[(by*32 + ty + q*8)*HID + bx*32 + tx];
    __syncthreads();
#pragma unroll
    for (int q = 0; q < 4; ++q)
        W1T[(bx*32 + ty + q*8)*HID + by*32 + tx] = tile[tx][ty + q*8];
}

__global__ __launch_bounds__(256, 2)
void lnn_fused(const float* __restrict__ x,
               const float* __restrict__ W0, const float* __restrict__ b0,
               const float* __restrict__ W1, const float* __restrict__ b1,
               const float* __restrict__ W2,
               const float* __restrict__ W1T, const int useT,
               float* __restrict__ out)
{
    __shared__ float M0[HID * SCP];
    __shared__ float U [HID * SCP];
    const int tid   = threadIdx.x;
    const int samp0 = blockIdx.x * TS8;
    {
        const int j = tid;
        float w0r[7];
#pragma unroll
        for (int d = 0; d < 7; ++d) w0r[d] = W0[j*7 + d];
        const float bj = b0[j];
#pragma unroll
        for (int s = 0; s < TS8; ++s) {
            const float* xs = x + (size_t)(samp0 + s)*7;
            float z = bj;
#pragma unroll
            for (int d = 0; d < 7; ++d) z = fmaf(w0r[d], xs[d], z);
            const float h  = tanhf(z);
            const float sg = 1.0f - h*h;
            float4 v = {h, sg * w0r[4], sg * w0r[5], sg * w0r[6]};
            *(float4*)(&M0[j*SCP + s*4]) = v;
        }
    }
    __syncthreads();
    const int it = tid & 63;
    const int ct = tid >> 6;
    float acc[4][8];
#pragma unroll
    for (int r = 0; r < 4; ++r)
#pragma unroll
        for (int c = 0; c < 8; ++c) acc[r][c] = 0.0f;
    if (useT) {
#pragma unroll 4
        for (int j = 0; j < HID; ++j) {
            const float4 w4 = *(const float4*)(W1T + (size_t)j*HID + it*4);
            const float4 ma = *(const float4*)(&M0[j*SCP + ct*8]);
            const float4 mb = *(const float4*)(&M0[j*SCP + ct*8 + 4]);
            const float w[4] = {w4.x, w4.y, w4.z, w4.w};
            const float m[8] = {ma.x, ma.y, ma.z, ma.w, mb.x, mb.y, mb.z, mb.w};
#pragma unroll
            for (int r = 0; r < 4; ++r)
#pragma unroll
                for (int c = 0; c < 8; ++c)
                    acc[r][c] = fmaf(w[r], m[c], acc[r][c]);
        }
    } else {
#pragma unroll 2
        for (int j = 0; j < HID; ++j) {
            float w[4];
#pragma unroll
            for (int r = 0; r < 4; ++r) w[r] = W1[(size_t)(it*4 + r)*HID + j];
            const float4 ma = *(const float4*)(&M0[j*SCP + ct*8]);
            const float4 mb = *(const float4*)(&M0[j*SCP + ct*8 + 4]);
            const float m[8] = {ma.x, ma.y, ma.z, ma.w, mb.x, mb.y, mb.z, mb.w};
#pragma unroll
            for (int r = 0; r < 4; ++r)
#pragma unroll
                for (int c = 0; c < 8; ++c)
                    acc[r][c] = fmaf(w[r], m[c], acc[r][c]);
        }
    }
    {
#pragma unroll
        for (int r = 0; r < 4; ++r) {
            const int i = it*4 + r;
            const float b1i = b1[i];
            const float w2i = W2[i];
#pragma unroll
            for (int cs = 0; cs < 2; ++cs) {
                const float z1 = acc[r][cs*4+0] + b1i;
                const float h1 = tanhf(z1);
                const float s1 = 1.0f - h1*h1;
                float4 uv;
                uv.x = w2i * s1;
                const float m2 = -2.0f * w2i * h1 * s1;
                uv.y = m2 * acc[r][cs*4+1];
                uv.z = m2 * acc[r][cs*4+2];
                uv.w = m2 * acc[r][cs*4+3];
                *(float4*)(&U[i*SCP + ct*8 + cs*4]) = uv;
            }
        }
    }
    __syncthreads();
    float acc2[4][8];
#pragma unroll
    for (int r = 0; r < 4; ++r)
#pragma unroll
        for (int c = 0; c < 8; ++c) acc2[r][c] = 0.0f;
#pragma unroll 4
    for (int i = 0; i < HID; ++i) {
        const float4 w4 = *(const float4*)(W1 + (size_t)i*HID + it*4);
        const float4 ua = *(const float4*)(&U[i*SCP + ct*8]);
        const float4 ub = *(const float4*)(&U[i*SCP + ct*8 + 4]);
        const float w[4] = {w4.x, w4.y, w4.z, w4.w};
        const float m[8] = {ua.x, ua.y, ua.z, ua.w, ub.x, ub.y, ub.z, ub.w};
#pragma unroll
        for (int r = 0; r < 4; ++r)
#pragma unroll
            for (int c = 0; c < 8; ++c)
                acc2[r][c] = fmaf(w[r], m[c], acc2[r][c]);
    }
    __syncthreads();
    {
#pragma unroll
        for (int r = 0; r < 4; ++r) {
            const int j = it*4 + r;
#pragma unroll
            for (int cs = 0; cs < 2; ++cs) {
                const int scb = ct*8 + cs*4;
                const float4 mm = *(const float4*)(&M0[j*SCP + scb]);
                const float h0v = mm.x;
                const float sg  = 1.0f - h0v*h0v;
                const float p   = acc2[r][cs*4+0];
                const float t2  = -2.0f * p * h0v;
                float4 uv;
                uv.x = p * sg;
                uv.y = fmaf(acc2[r][cs*4+1], sg, t2 * mm.y);
                uv.z = fmaf(acc2[r][cs*4+2], sg, t2 * mm.z);
                uv.w = fmaf(acc2[r][cs*4+3], sg, t2 * mm.w);
                *(float4*)(&U[j*SCP + scb]) = uv;
            }
        }
    }
    __syncthreads();
    const int s = tid >> 5;
    const int t = tid & 31;
    float part[25];
#pragma unroll
    for (int qq = 0; qq < 25; ++qq) part[qq] = 0.0f;
#pragma unroll
    for (int m = 0; m < 8; ++m) {
        const int j = t + 32*m;
        const float4 uv = *(const float4*)(&U[j*SCP + s*4]);
        float w0d[7];
#pragma unroll
        for (int d = 0; d < 7; ++d) w0d[d] = W0[j*7 + d];
#pragma unroll
        for (int d = 0; d < 4; ++d) part[d] = fmaf(uv.x, w0d[d], part[d]);
#pragma unroll
        for (int d = 0; d < 7; ++d) {
            part[4  + d] = fmaf(uv.y, w0d[d], part[4  + d]);
            part[11 + d] = fmaf(uv.z, w0d[d], part[11 + d]);
            part[18 + d] = fmaf(uv.w, w0d[d], part[18 + d]);
        }
    }
#pragma unroll
    for (int off = 16; off >= 1; off >>= 1)
#pragma unroll
        for (int qq = 0; qq < 25; ++qq)
            part[qq] += __shfl_xor(part[qq], off, 64);
    if (t == 0) {
        const float* xs = x + (size_t)(samp0 + s)*7;
        const double x1 = xs[2], x2 = xs[3];
        const double dq0 = xs[4], dq1 = xs[5], dth = xs[6];
        double A[3][4];
#pragma unroll
        for (int i = 0; i < 3; ++i) {
            const double J0 = part[4 + i*7 + 0];
            const double J1 = part[4 + i*7 + 1];
            const double J2 = -x2*(double)part[4 + i*7 + 2] + x1*(double)part[4 + i*7 + 3];
            const double dL = (i == 0) ? (double)part[0]
                            : (i == 1) ? (double)part[1]
                            : (-x2*(double)part[2] + x1*(double)part[3]);
            A[i][0] = (double)part[4 + i*7 + 4] + (i == 0 ? EPS_REG : 0.0);
            A[i][1] = (double)part[4 + i*7 + 5] + (i == 1 ? EPS_REG : 0.0);
            A[i][2] = (double)part[4 + i*7 + 6] + (i == 2 ? EPS_REG : 0.0);
            A[i][3] = dL - (J0*dq0 + J1*dq1 + J2*dth);
        }
        for (int cc = 0; cc < 2; ++cc) {
            int piv = cc;
            double mx = fabs(A[cc][cc]);
            for (int rr = cc + 1; rr < 3; ++rr) {
                const double v = fabs(A[rr][cc]);
                if (v > mx) { mx = v; piv = rr; }
            }
            if (piv != cc) {
                for (int k2 = 0; k2 < 4; ++k2) {
                    const double tmp = A[cc][k2]; A[cc][k2] = A[piv][k2]; A[piv][k2] = tmp;
                }
            }
            const double inv = 1.0 / A[cc][cc];
            for (int rr = cc + 1; rr < 3; ++rr) {
                const double f = A[rr][cc] * inv;
                for (int k2 = cc + 1; k2 < 4; ++k2) A[rr][k2] -= f * A[cc][k2];
            }
        }
        const double sol2 = A[2][3] / A[2][2];
        const double sol1 = (A[1][3] - A[1][2]*sol2) / A[1][1];
        const double sol0 = (A[0][3] - A[0][1]*sol1 - A[0][2]*sol2) / A[0][0];
        float* o = out + (size_t)(samp0 + s)*7;
        o[0] = (float)dq0;
        o[1] = (float)dq1;
        o[2] = (float)(-x2*dth);
        o[3] = (float)( x1*dth);
        o[4] = (float)sol0;
        o[5] = (float)sol1;
        o[6] = (float)sol2;
    }
}

extern "C" void kernel_launch(void* const* d_in, const int* in_sizes, int n_in,
                              void* d_out, int out_size, void* d_ws, size_t ws_size,
                              hipStream_t stream) {
    const float* x  = (const float*)d_in[0];
    const float* W0 = (const float*)d_in[1];
    const float* b0 = (const float*)d_in[2];
    const float* W1 = (const float*)d_in[3];
    const float* b1 = (const float*)d_in[4];
    const float* W2 = (const float*)d_in[5];
    float* out = (float*)d_out;

    const int B = in_sizes[0] / 7;
    const size_t NEED = 6u * 65536u * sizeof(short);   // 768 KB of W1 fragments

    if (ws_size >= NEED && (B % 8) == 0) {
        short* ws = (short*)d_ws;
        prep_w1_frags<<<128, 128, 0, stream>>>(W1, ws);
        lnn_mfma<<<B / 8, 512, 0, stream>>>(x, W0, b0, b1, W2, ws, out);
    } else {
        const int useT = (ws_size >= (size_t)HID * HID * sizeof(float)) ? 1 : 0;
        float* W1T = (float*)d_ws;
        if (useT) transpose_w1<<<64, 256, 0, stream>>>(W1, W1T);
        lnn_fused<<<B / TS8, 256, 0, stream>>>(x, W0, b0, W1, b1, W2, W1T, useT, out);
    }
}

// Round 13
// 270.393 us; speedup vs baseline: 1.0174x; 1.0174x over previous
//
#include <hip/hip_runtime.h>
#include <math.h>

#define HID 256
#define EPS_REG 1e-6

typedef __attribute__((ext_vector_type(8))) short short8;
typedef __attribute__((ext_vector_type(4))) short short4v;
typedef __attribute__((ext_vector_type(4))) float v4f;

#define MFMA_BF16(a, b, c) __builtin_amdgcn_mfma_f32_16x16x32_bf16((a), (b), (c), 0, 0, 0)

// ---------------------------------------------------------------------------
// Fast tanh: tanh(z) = 1 - 2/(exp(2z)+1). ~6 instr, <=2 ulp.
// ---------------------------------------------------------------------------
__device__ __forceinline__ float fast_tanh(float z) {
    const float e = __expf(2.0f * z);
    const float d = e + 1.0f;
    float r = __builtin_amdgcn_rcpf(d);
    r = r * (2.0f - d * r);              // Newton refine to full fp32
    return fmaf(-2.0f, r, 1.0f);
}

// ---------------------------------------------------------------------------
// Cheap RTN bf16 3-way split: v ~= hi + mid + lo (round-half-up, 2 ops/stage).
// ---------------------------------------------------------------------------
__device__ __forceinline__ float rtn_bf16(float v, short* s) {
    unsigned r = (__float_as_uint(v) + 0x8000u) & 0xFFFF0000u;
    *s = (short)(r >> 16);
    return __uint_as_float(r);
}
__device__ __forceinline__ void split3(float v, short* a, short* b, short* c) {
    float f0 = rtn_bf16(v, a);
    float r1 = v - f0;
    float f1 = rtn_bf16(r1, b);
    float r2 = r1 - f1;
    (void)rtn_bf16(r2, c);
}

// ---------------------------------------------------------------------------
// Prep: split W1 into bf16 hi/mid/lo laid out as per-lane MFMA A-fragments
// for phase 1 (A = W1 rows) and phase 2 (A = W1 columns). 6 x 128KB = 768KB.
// ---------------------------------------------------------------------------
__global__ void prep_w1_frags(const float* __restrict__ W1, short* __restrict__ ws) {
    const int gid   = blockIdx.x * 128 + threadIdx.x;   // 0..16383
    const int lane  = gid & 63;
    const int ks    = (gid >> 6) & 7;
    const int rt    = (gid >> 9) & 15;
    const int which = gid >> 13;                        // 0: A1, 1: A2
    const int m = lane & 15, q = lane >> 4;

    float v[8];
    if (which == 0) {
        const float* p = W1 + (size_t)(rt*16 + m)*HID + ks*32 + q*8;
        const float4 va = *(const float4*)(p);
        const float4 vb = *(const float4*)(p + 4);
        v[0]=va.x; v[1]=va.y; v[2]=va.z; v[3]=va.w;
        v[4]=vb.x; v[5]=vb.y; v[6]=vb.z; v[7]=vb.w;
    } else {
        const float* p = W1 + (size_t)(ks*32 + q*8)*HID + rt*16 + m;
#pragma unroll
        for (int t = 0; t < 8; ++t) v[t] = p[(size_t)t*HID];
    }
    short8 h8, m8, l8;
#pragma unroll
    for (int t = 0; t < 8; ++t) {
        short sh, sm, sl;
        split3(v[t], &sh, &sm, &sl);
        h8[t] = sh; m8[t] = sm; l8[t] = sl;
    }
    const size_t base = (size_t)which*3*65536 + ((size_t)(rt*8 + ks)*64 + lane)*8;
    *(short8*)(ws + base)          = h8;
    *(short8*)(ws + base + 65536)  = m8;
    *(short8*)(ws + base + 131072) = l8;
}

// ---------------------------------------------------------------------------
// MFMA main kernel: 8 samples/block (N=32 = 2 col-tiles), 512 threads = 8
// waves (2 row-tiles/wave), 2 blocks/CU -> 4 waves/SIMD.
// bf16x3 / 6-product fp32 emulation on 16x16x32 MFMA.
// B-frag layout: addr = G*136 + c*8 + (k&7), G = k>>3 (16B pad per group).
// R13: revert of R12's U0 XOR-swizzle (it RAISED conflicts 1.42e7->1.52e7 --
// the pinned conflict count is irreducible multi-bank occupancy of wide LDS
// ops, not a fixable pattern). This is the best-measured R11 kernel.
// ---------------------------------------------------------------------------
#define FRAG_NT_STRIDE 13056   // 3 bufs * 32 groups * 136 shorts
#define FRAG_BUF_STRIDE 4352   // 32 groups * 136

__global__ __launch_bounds__(512, 4)
void lnn_mfma(const float* __restrict__ x,
              const float* __restrict__ W0, const float* __restrict__ b0,
              const float* __restrict__ b1, const float* __restrict__ W2,
              const short* __restrict__ ws,
              float* __restrict__ out)
{
    __shared__ __align__(16) short Bfrag[26112];     // 52224 B
    __shared__ float M0h[HID * 9];                   // h0 per (j, s), stride 9

    const int tid   = threadIdx.x;
    const int samp0 = blockIdx.x * 8;
    const int lane  = tid & 63;
    const int w     = tid >> 6;                      // wave 0..7

    // ---- Phase 0: layer-0 forward + tangents --> M0h + B1 frags -----------
    {
        const int j  = tid & 255;
        const int s0 = (tid >> 8) * 4;
        float w0r[7];
#pragma unroll
        for (int d = 0; d < 7; ++d) w0r[d] = W0[j*7 + d];
        const float bj = b0[j];
        const int kbase = (j >> 3)*136 + (j & 7);    // G*136 + t
#pragma unroll
        for (int si = 0; si < 4; ++si) {
            const int s = s0 + si;
            const float* xs = x + (size_t)(samp0 + s)*7;
            float z = bj;
#pragma unroll
            for (int d = 0; d < 7; ++d) z = fmaf(w0r[d], xs[d], z);
            const float h  = fast_tanh(z);
            const float sg = 1.0f - h*h;
            M0h[j*9 + s] = h;
            const int nt = s >> 2;
            const int cb = (s & 3) * 4;              // col base within tile
            float vals[4] = {h, sg*w0r[4], sg*w0r[5], sg*w0r[6]};
#pragma unroll
            for (int comp = 0; comp < 4; ++comp) {
                short sh, sm, sl;
                split3(vals[comp], &sh, &sm, &sl);
                const int a = nt*FRAG_NT_STRIDE + kbase + (cb + comp)*8;
                Bfrag[a]                    = sh;
                Bfrag[a + FRAG_BUF_STRIDE]  = sm;
                Bfrag[a + 2*FRAG_BUF_STRIDE]= sl;
            }
        }
    }
    __syncthreads();

    const short8* A1h = (const short8*)ws;
    const short8* A1m = A1h + 8192;
    const short8* A1l = A1h + 16384;
    const short8* A2h = A1h + 24576;
    const short8* A2m = A1h + 32768;
    const short8* A2l = A1h + 40960;

    const int q = lane >> 4;        // C/D row-quad; also B k-octet
    const int c = lane & 15;        // C/D & B col
    const int boff = q*136 + c*8;   // per-lane B-frag offset within (nt,buf,ks=0)

    // ---- Phase 1: Z = W1 x M  (rows i = (w*2+rtl)*16 + q*4 + reg) ---------
    v4f acc[2][2];
#pragma unroll
    for (int rtl = 0; rtl < 2; ++rtl)
#pragma unroll
        for (int nt = 0; nt < 2; ++nt) acc[rtl][nt] = (v4f){0.f, 0.f, 0.f, 0.f};

    {
        short8 pah[2][2], pam[2][2], pal[2][2];   // [parity][rtl] A prefetch
#pragma unroll
        for (int rtl = 0; rtl < 2; ++rtl) {
            const size_t fi = ((size_t)((w*2 + rtl)*8))*64 + lane;
            pah[0][rtl] = A1h[fi]; pam[0][rtl] = A1m[fi]; pal[0][rtl] = A1l[fi];
        }
#pragma unroll
        for (int ks = 0; ks < 8; ++ks) {
            const int cur = ks & 1, nxt = cur ^ 1;
            if (ks < 7) {
#pragma unroll
                for (int rtl = 0; rtl < 2; ++rtl) {
                    const size_t fi = ((size_t)((w*2 + rtl)*8 + ks + 1))*64 + lane;
                    pah[nxt][rtl] = A1h[fi]; pam[nxt][rtl] = A1m[fi]; pal[nxt][rtl] = A1l[fi];
                }
            }
            short8 bh[2], bm[2], bl[2];
#pragma unroll
            for (int nt = 0; nt < 2; ++nt) {
                const int a = nt*FRAG_NT_STRIDE + ks*544 + boff;
                bh[nt] = *(const short8*)(&Bfrag[a]);
                bm[nt] = *(const short8*)(&Bfrag[a + FRAG_BUF_STRIDE]);
                bl[nt] = *(const short8*)(&Bfrag[a + 2*FRAG_BUF_STRIDE]);
            }
#pragma unroll
            for (int rtl = 0; rtl < 2; ++rtl) {
                const short8 ah = pah[cur][rtl];
                const short8 am = pam[cur][rtl];
                const short8 al = pal[cur][rtl];
#pragma unroll
                for (int nt = 0; nt < 2; ++nt) {
                    acc[rtl][nt] = MFMA_BF16(ah, bl[nt], acc[rtl][nt]);
                    acc[rtl][nt] = MFMA_BF16(al, bh[nt], acc[rtl][nt]);
                    acc[rtl][nt] = MFMA_BF16(am, bm[nt], acc[rtl][nt]);
                    acc[rtl][nt] = MFMA_BF16(am, bh[nt], acc[rtl][nt]);
                    acc[rtl][nt] = MFMA_BF16(ah, bm[nt], acc[rtl][nt]);
                    acc[rtl][nt] = MFMA_BF16(ah, bh[nt], acc[rtl][nt]);
                }
            }
        }
    }
    __syncthreads();   // all waves done reading B1 frags

    // ---- Epilogue 1: layer-2 nonlinearity + reverse seed --> B2 frags -----
    {
        const int myreg = c & 3;
#pragma unroll
        for (int rtl = 0; rtl < 2; ++rtl) {
            const int base = (w*2 + rtl)*16;
            float b1r[4], w2r[4];
#pragma unroll
            for (int r = 0; r < 4; ++r) {
                b1r[r] = b1[base + q*4 + r];
                w2r[r] = W2[base + q*4 + r];
            }
            const int G  = (base >> 3) + (q >> 1);
            const int tq = (q & 1) * 4;
#pragma unroll
            for (int nt = 0; nt < 2; ++nt) {
                short4v ph, pm, pl;
#pragma unroll
                for (int r = 0; r < 4; ++r) {
                    const float z0 = __shfl(acc[rtl][nt][r] + b1r[r], lane & ~3, 64);
                    const float h1 = fast_tanh(z0);
                    const float s1 = 1.0f - h1*h1;
                    const float av = acc[rtl][nt][r];
                    const float u  = (myreg == 0) ? (w2r[r]*s1)
                                                  : (-2.0f*w2r[r]*h1*s1)*av;
                    short sh, sm, sl;
                    split3(u, &sh, &sm, &sl);
                    ph[r] = sh; pm[r] = sm; pl[r] = sl;
                }
                const int a = nt*FRAG_NT_STRIDE + G*136 + c*8 + tq;
                *(short4v*)(&Bfrag[a])                     = ph;
                *(short4v*)(&Bfrag[a + FRAG_BUF_STRIDE])   = pm;
                *(short4v*)(&Bfrag[a + 2*FRAG_BUF_STRIDE]) = pl;
            }
        }
    }
    __syncthreads();

    // ---- Phase 2: P = W1^T x U  (rows j = (w*2+rtl)*16 + q*4 + reg) -------
    v4f acc2[2][2];
#pragma unroll
    for (int rtl = 0; rtl < 2; ++rtl)
#pragma unroll
        for (int nt = 0; nt < 2; ++nt) acc2[rtl][nt] = (v4f){0.f, 0.f, 0.f, 0.f};

    {
        short8 pah[2][2], pam[2][2], pal[2][2];
#pragma unroll
        for (int rtl = 0; rtl < 2; ++rtl) {
            const size_t fi = ((size_t)((w*2 + rtl)*8))*64 + lane;
            pah[0][rtl] = A2h[fi]; pam[0][rtl] = A2m[fi]; pal[0][rtl] = A2l[fi];
        }
#pragma unroll
        for (int ks = 0; ks < 8; ++ks) {
            const int cur = ks & 1, nxt = cur ^ 1;
            if (ks < 7) {
#pragma unroll
                for (int rtl = 0; rtl < 2; ++rtl) {
                    const size_t fi = ((size_t)((w*2 + rtl)*8 + ks + 1))*64 + lane;
                    pah[nxt][rtl] = A2h[fi]; pam[nxt][rtl] = A2m[fi]; pal[nxt][rtl] = A2l[fi];
                }
            }
            short8 bh[2], bm[2], bl[2];
#pragma unroll
            for (int nt = 0; nt < 2; ++nt) {
                const int a = nt*FRAG_NT_STRIDE + ks*544 + boff;
                bh[nt] = *(const short8*)(&Bfrag[a]);
                bm[nt] = *(const short8*)(&Bfrag[a + FRAG_BUF_STRIDE]);
                bl[nt] = *(const short8*)(&Bfrag[a + 2*FRAG_BUF_STRIDE]);
            }
#pragma unroll
            for (int rtl = 0; rtl < 2; ++rtl) {
                const short8 ah = pah[cur][rtl];
                const short8 am = pam[cur][rtl];
                const short8 al = pal[cur][rtl];
#pragma unroll
                for (int nt = 0; nt < 2; ++nt) {
                    acc2[rtl][nt] = MFMA_BF16(ah, bl[nt], acc2[rtl][nt]);
                    acc2[rtl][nt] = MFMA_BF16(al, bh[nt], acc2[rtl][nt]);
                    acc2[rtl][nt] = MFMA_BF16(am, bm[nt], acc2[rtl][nt]);
                    acc2[rtl][nt] = MFMA_BF16(am, bh[nt], acc2[rtl][nt]);
                    acc2[rtl][nt] = MFMA_BF16(ah, bm[nt], acc2[rtl][nt]);
                    acc2[rtl][nt] = MFMA_BF16(ah, bh[nt], acc2[rtl][nt]);
                }
            }
        }
    }
    __syncthreads();   // all waves done reading B2 frags

    // ---- Epilogue 2: back through layer-0 --> U0 plain (overlay Bfrag) ----
    {
        float* U0 = (float*)Bfrag;      // [j][s*4+comp], stride 36
#pragma unroll
        for (int rtl = 0; rtl < 2; ++rtl) {
#pragma unroll
            for (int reg = 0; reg < 4; ++reg) {
                const int j = (w*2 + rtl)*16 + q*4 + reg;
                const float w0sel = W0[j*7 + 3 + (c & 3)];  // dummy read for comp 0
#pragma unroll
                for (int nt = 0; nt < 2; ++nt) {
                    const int s = nt*4 + (c >> 2);
                    const float pv = acc2[rtl][nt][reg];
                    const float p0 = __shfl(pv, lane & ~3, 64);
                    const float h0 = M0h[j*9 + s];
                    const float sg = 1.0f - h0*h0;
                    const float t2 = -2.0f * p0 * h0 * sg;
                    const float res = ((c & 3) == 0) ? (p0*sg)
                                                     : fmaf(pv, sg, t2 * w0sel);
                    U0[j*36 + s*4 + (c & 3)] = res;
                }
            }
        }
    }
    __syncthreads();

    // ---- Phase 3: project through W0^T, reduce, assemble, solve -----------
    const float* U0 = (const float*)Bfrag;
    float* scratch = ((float*)Bfrag) + 9216 + w * 425;   // [25][17]
    const int s = w;            // sample (0..7) = wave id
    const int t = tid & 63;
    float part[25];
#pragma unroll
    for (int qq = 0; qq < 25; ++qq) part[qq] = 0.0f;

#pragma unroll
    for (int m = 0; m < 4; ++m) {
        const int j = t + 64*m;
        const float4 uv = *(const float4*)(&U0[j*36 + s*4]);
        float w0d[7];
#pragma unroll
        for (int d = 0; d < 7; ++d) w0d[d] = W0[j*7 + d];
#pragma unroll
        for (int d = 0; d < 4; ++d) part[d] = fmaf(uv.x, w0d[d], part[d]);
#pragma unroll
        for (int d = 0; d < 7; ++d) {
            part[4  + d] = fmaf(uv.y, w0d[d], part[4  + d]);
            part[11 + d] = fmaf(uv.z, w0d[d], part[11 + d]);
            part[18 + d] = fmaf(uv.w, w0d[d], part[18 + d]);
        }
    }
    // stages 1-2: quad-local sums
#pragma unroll
    for (int off = 1; off <= 2; off <<= 1)
#pragma unroll
        for (int qq = 0; qq < 25; ++qq)
            part[qq] += __shfl_xor(part[qq], off, 64);
    {
        const int quad = t >> 2;
        if ((t & 3) == 0) {
#pragma unroll
            for (int e = 0; e < 25; ++e)
                scratch[e*17 + quad] = part[e];
        }
    }
    if (t < 25) {
        float tot = 0.0f;
#pragma unroll
        for (int k = 0; k < 16; ++k) tot += scratch[t*17 + k];
        scratch[t*17 + 16] = tot;
    }

    if (t == 0) {
        double g[25];
#pragma unroll
        for (int e = 0; e < 25; ++e) g[e] = (double)scratch[e*17 + 16];

        const float* xs = x + (size_t)(samp0 + s)*7;
        const double x1 = xs[2], x2 = xs[3];
        const double dq0 = xs[4], dq1 = xs[5], dth = xs[6];

        double M[3][3], rhs[3];
#pragma unroll
        for (int i = 0; i < 3; ++i) {
            const double J0 = g[4 + i*7 + 0];
            const double J1 = g[4 + i*7 + 1];
            const double J2 = -x2*g[4 + i*7 + 2] + x1*g[4 + i*7 + 3];
            const double dL = (i == 0) ? g[0]
                            : (i == 1) ? g[1]
                            : (-x2*g[2] + x1*g[3]);
            M[i][0] = g[4 + i*7 + 4] + (i == 0 ? EPS_REG : 0.0);
            M[i][1] = g[4 + i*7 + 5] + (i == 1 ? EPS_REG : 0.0);
            M[i][2] = g[4 + i*7 + 6] + (i == 2 ? EPS_REG : 0.0);
            rhs[i]  = dL - (J0*dq0 + J1*dq1 + J2*dth);
        }
        // branch-free fp64 Cramer / adjugate solve
        const double c00 = M[1][1]*M[2][2] - M[1][2]*M[2][1];
        const double c01 = M[1][2]*M[2][0] - M[1][0]*M[2][2];
        const double c02 = M[1][0]*M[2][1] - M[1][1]*M[2][0];
        const double det = M[0][0]*c00 + M[0][1]*c01 + M[0][2]*c02;
        const double inv = 1.0 / det;
        const double c10 = M[0][2]*M[2][1] - M[0][1]*M[2][2];
        const double c11 = M[0][0]*M[2][2] - M[0][2]*M[2][0];
        const double c12 = M[0][1]*M[2][0] - M[0][0]*M[2][1];
        const double c20 = M[0][1]*M[1][2] - M[0][2]*M[1][1];
        const double c21 = M[0][2]*M[1][0] - M[0][0]*M[1][2];
        const double c22 = M[0][0]*M[1][1] - M[0][1]*M[1][0];
        const double sol0 = (c00*rhs[0] + c10*rhs[1] + c20*rhs[2]) * inv;
        const double sol1 = (c01*rhs[0] + c11*rhs[1] + c21*rhs[2]) * inv;
        const double sol2 = (c02*rhs[0] + c12*rhs[1] + c22*rhs[2]) * inv;

        float* o = out + (size_t)(samp0 + s)*7;
        o[0] = (float)dq0;
        o[1] = (float)dq1;
        o[2] = (float)(-x2*dth);
        o[3] = (float)( x1*dth);
        o[4] = (float)sol0;
        o[5] = (float)sol1;
        o[6] = (float)sol2;
    }
}

// ===========================================================================
// Fallback path (proven round-3 kernel, fp32 VALU): used if ws_size < 768KB.
// ===========================================================================
#define TS8 8
#define SCP 36

__global__ void transpose_w1(const float* __restrict__ W1, float* __restrict__ W1T) {
    __shared__ float tile[32][33];
    const int bx = blockIdx.x & 7;
    const int by = blockIdx.x >> 3;
    const int tx = threadIdx.x & 31;
    const int ty = threadIdx.x >> 5;
#pragma unroll
    for (int q = 0; q < 4; ++q)
        tile[ty + q*8][tx] = W1[(by*32 + ty + q*8)*HID + bx*32 + tx];
    __syncthreads();
#pragma unroll
    for (int q = 0; q < 4; ++q)
        W1T[(bx*32 + ty + q*8)*HID + by*32 + tx] = tile[tx][ty + q*8];
}

__global__ __launch_bounds__(256, 2)
void lnn_fused(const float* __restrict__ x,
               const float* __restrict__ W0, const float* __restrict__ b0,
               const float* __restrict__ W1, const float* __restrict__ b1,
               const float* __restrict__ W2,
               const float* __restrict__ W1T, const int useT,
               float* __restrict__ out)
{
    __shared__ float M0[HID * SCP];
    __shared__ float U [HID * SCP];
    const int tid   = threadIdx.x;
    const int samp0 = blockIdx.x * TS8;
    {
        const int j = tid;
        float w0r[7];
#pragma unroll
        for (int d = 0; d < 7; ++d) w0r[d] = W0[j*7 + d];
        const float bj = b0[j];
#pragma unroll
        for (int s = 0; s < TS8; ++s) {
            const float* xs = x + (size_t)(samp0 + s)*7;
            float z = bj;
#pragma unroll
            for (int d = 0; d < 7; ++d) z = fmaf(w0r[d], xs[d], z);
            const float h  = tanhf(z);
            const float sg = 1.0f - h*h;
            float4 v = {h, sg * w0r[4], sg * w0r[5], sg * w0r[6]};
            *(float4*)(&M0[j*SCP + s*4]) = v;
        }
    }
    __syncthreads();
    const int it = tid & 63;
    const int ct = tid >> 6;
    float acc[4][8];
#pragma unroll
    for (int r = 0; r < 4; ++r)
#pragma unroll
        for (int c = 0; c < 8; ++c) acc[r][c] = 0.0f;
    if (useT) {
#pragma unroll 4
        for (int j = 0; j < HID; ++j) {
            const float4 w4 = *(const float4*)(W1T + (size_t)j*HID + it*4);
            const float4 ma = *(const float4*)(&M0[j*SCP + ct*8]);
            const float4 mb = *(const float4*)(&M0[j*SCP + ct*8 + 4]);
            const float w[4] = {w4.x, w4.y, w4.z, w4.w};
            const float m[8] = {ma.x, ma.y, ma.z, ma.w, mb.x, mb.y, mb.z, mb.w};
#pragma unroll
            for (int r = 0; r < 4; ++r)
#pragma unroll
                for (int c = 0; c < 8; ++c)
                    acc[r][c] = fmaf(w[r], m[c], acc[r][c]);
        }
    } else {
#pragma unroll 2
        for (int j = 0; j < HID; ++j) {
            float w[4];
#pragma unroll
            for (int r = 0; r < 4; ++r) w[r] = W1[(size_t)(it*4 + r)*HID + j];
            const float4 ma = *(const float4*)(&M0[j*SCP + ct*8]);
            const float4 mb = *(const float4*)(&M0[j*SCP + ct*8 + 4]);
            const float m[8] = {ma.x, ma.y, ma.z, ma.w, mb.x, mb.y, mb.z, mb.w};
#pragma unroll
            for (int r = 0; r < 4; ++r)
#pragma unroll
                for (int c = 0; c < 8; ++c)
                    acc[r][c] = fmaf(w[r], m[c], acc[r][c]);
        }
    }
    {
#pragma unroll
        for (int r = 0; r < 4; ++r) {
            const int i = it*4 + r;
            const float b1i = b1[i];
            const float w2i = W2[i];
#pragma unroll
            for (int cs = 0; cs < 2; ++cs) {
                const float z1 = acc[r][cs*4+0] + b1i;
                const float h1 = tanhf(z1);
                const float s1 = 1.0f - h1*h1;
                float4 uv;
                uv.x = w2i * s1;
                const float m2 = -2.0f * w2i * h1 * s1;
                uv.y = m2 * acc[r][cs*4+1];
                uv.z = m2 * acc[r][cs*4+2];
                uv.w = m2 * acc[r][cs*4+3];
                *(float4*)(&U[i*SCP + ct*8 + cs*4]) = uv;
            }
        }
    }
    __syncthreads();
    float acc2[4][8];
#pragma unroll
    for (int r = 0; r < 4; ++r)
#pragma unroll
        for (int c = 0; c < 8; ++c) acc2[r][c] = 0.0f;
#pragma unroll 4
    for (int i = 0; i < HID; ++i) {
        const float4 w4 = *(const float4*)(W1 + (size_t)i*HID + it*4);
        const float4 ua = *(const float4*)(&U[i*SCP + ct*8]);
        const float4 ub = *(const float4*)(&U[i*SCP + ct*8 + 4]);
        const float w[4] = {w4.x, w4.y, w4.z, w4.w};
        const float m[8] = {ua.x, ua.y, ua.z, ua.w, ub.x, ub.y, ub.z, ub.w};
#pragma unroll
        for (int r = 0; r < 4; ++r)
#pragma unroll
            for (int c = 0; c < 8; ++c)
                acc2[r][c] = fmaf(w[r], m[c], acc2[r][c]);
    }
    __syncthreads();
    {
#pragma unroll
        for (int r = 0; r < 4; ++r) {
            const int j = it*4 + r;
#pragma unroll
            for (int cs = 0; cs < 2; ++cs) {
                const int scb = ct*8 + cs*4;
                const float4 mm = *(const float4*)(&M0[j*SCP + scb]);
                const float h0v = mm.x;
                const float sg  = 1.0f - h0v*h0v;
                const float p   = acc2[r][cs*4+0];
                const float t2  = -2.0f * p * h0v;
                float4 uv;
                uv.x = p * sg;
                uv.y = fmaf(acc2[r][cs*4+1], sg, t2 * mm.y);
                uv.z = fmaf(acc2[r][cs*4+2], sg, t2 * mm.z);
                uv.w = fmaf(acc2[r][cs*4+3], sg, t2 * mm.w);
                *(float4*)(&U[j*SCP + scb]) = uv;
            }
        }
    }
    __syncthreads();
    const int s = tid >> 5;
    const int t = tid & 31;
    float part[25];
#pragma unroll
    for (int qq = 0; qq < 25; ++qq) part[qq] = 0.0f;
#pragma unroll
    for (int m = 0; m < 8; ++m) {
        const int j = t + 32*m;
        const float4 uv = *(const float4*)(&U[j*SCP + s*4]);
        float w0d[7];
#pragma unroll
        for (int d = 0; d < 7; ++d) w0d[d] = W0[j*7 + d];
#pragma unroll
        for (int d = 0; d < 4; ++d) part[d] = fmaf(uv.x, w0d[d], part[d]);
#pragma unroll
        for (int d = 0; d < 7; ++d) {
            part[4  + d] = fmaf(uv.y, w0d[d], part[4  + d]);
            part[11 + d] = fmaf(uv.z, w0d[d], part[11 + d]);
            part[18 + d] = fmaf(uv.w, w0d[d], part[18 + d]);
        }
    }
#pragma unroll
    for (int off = 16; off >= 1; off >>= 1)
#pragma unroll
        for (int qq = 0; qq < 25; ++qq)
            part[qq] += __shfl_xor(part[qq], off, 64);
    if (t == 0) {
        const float* xs = x + (size_t)(samp0 + s)*7;
        const double x1 = xs[2], x2 = xs[3];
        const double dq0 = xs[4], dq1 = xs[5], dth = xs[6];
        double A[3][4];
#pragma unroll
        for (int i = 0; i < 3; ++i) {
            const double J0 = part[4 + i*7 + 0];
            const double J1 = part[4 + i*7 + 1];
            const double J2 = -x2*(double)part[4 + i*7 + 2] + x1*(double)part[4 + i*7 + 3];
            const double dL = (i == 0) ? (double)part[0]
                            : (i == 1) ? (double)part[1]
                            : (-x2*(double)part[2] + x1*(double)part[3]);
            A[i][0] = (double)part[4 + i*7 + 4] + (i == 0 ? EPS_REG : 0.0);
            A[i][1] = (double)part[4 + i*7 + 5] + (i == 1 ? EPS_REG : 0.0);
            A[i][2] = (double)part[4 + i*7 + 6] + (i == 2 ? EPS_REG : 0.0);
            A[i][3] = dL - (J0*dq0 + J1*dq1 + J2*dth);
        }
        for (int cc = 0; cc < 2; ++cc) {
            int piv = cc;
            double mx = fabs(A[cc][cc]);
            for (int rr = cc + 1; rr < 3; ++rr) {
                const double v = fabs(A[rr][cc]);
                if (v > mx) { mx = v; piv = rr; }
            }
            if (piv != cc) {
                for (int k2 = 0; k2 < 4; ++k2) {
                    const double tmp = A[cc][k2]; A[cc][k2] = A[piv][k2]; A[piv][k2] = tmp;
                }
            }
            const double inv = 1.0 / A[cc][cc];
            for (int rr = cc + 1; rr < 3; ++rr) {
                const double f = A[rr][cc] * inv;
                for (int k2 = cc + 1; k2 < 4; ++k2) A[rr][k2] -= f * A[cc][k2];
            }
        }
        const double sol2 = A[2][3] / A[2][2];
        const double sol1 = (A[1][3] - A[1][2]*sol2) / A[1][1];
        const double sol0 = (A[0][3] - A[0][1]*sol1 - A[0][2]*sol2) / A[0][0];
        float* o = out + (size_t)(samp0 + s)*7;
        o[0] = (float)dq0;
        o[1] = (float)dq1;
        o[2] = (float)(-x2*dth);
        o[3] = (float)( x1*dth);
        o[4] = (float)sol0;
        o[5] = (float)sol1;
        o[6] = (float)sol2;
    }
}

extern "C" void kernel_launch(void* const* d_in, const int* in_sizes, int n_in,
                              void* d_out, int out_size, void* d_ws, size_t ws_size,
                              hipStream_t stream) {
    const float* x  = (const float*)d_in[0];
    const float* W0 = (const float*)d_in[1];
    const float* b0 = (const float*)d_in[2];
    const float* W1 = (const float*)d_in[3];
    const float* b1 = (const float*)d_in[4];
    const float* W2 = (const float*)d_in[5];
    float* out = (float*)d_out;

    const int B = in_sizes[0] / 7;
    const size_t NEED = 6u * 65536u * sizeof(short);   // 768 KB of W1 fragments

    if (ws_size >= NEED && (B % 8) == 0) {
        short* ws = (short*)d_ws;
        prep_w1_frags<<<128, 128, 0, stream>>>(W1, ws);
        lnn_mfma<<<B / 8, 512, 0, stream>>>(x, W0, b0, b1, W2, ws, out);
    } else {
        const int useT = (ws_size >= (size_t)HID * HID * sizeof(float)) ? 1 : 0;
        float* W1T = (float*)d_ws;
        if (useT) transpose_w1<<<64, 256, 0, stream>>>(W1, W1T);
        lnn_fused<<<B / TS8, 256, 0, stream>>>(x, W0, b0, W1, b1, W2, W1T, useT, out);
    }
}